// Round 4
// baseline (364.079 us; speedup 1.0000x reference)
//
#include <hip/hip_runtime.h>
#include <math.h>

#define N_ROWS 32768
#define N_COLS 2048
constexpr float S_CONST = 1.05f;

// Butterfly reduction: result valid in ALL 64 lanes.
__device__ __forceinline__ float wred_sum(float v) {
    #pragma unroll
    for (int off = 32; off > 0; off >>= 1) v += __shfl_xor(v, off, 64);
    return v;
}

// Zero class accumulators + scalar output.
__global__ __launch_bounds__(256) void k_init(float* __restrict__ ws,
                                              float* __restrict__ out) {
    int i = blockIdx.x * 256 + threadIdx.x;
    if (i < 3 * N_COLS) ws[i] = 0.f;
    if (i == 0) out[0] = 0.f;
}

// PURE-STREAM rowpass: one wave per row, NO atomics, no LDS, no barriers.
// Per row: 8 dwordx4 loads/lane, three independent shfl butterflies, one
// dwordx4 store of {sum, sumsq, sumexp, target_logit}. Nothing competes
// with the 256 MB read stream.
__global__ __launch_bounds__(256) void k_rowpass(
    const float* __restrict__ X, const long long* __restrict__ lbl,
    float4* __restrict__ row_stats)
{
    const int lane = threadIdx.x & 63;
    const int row  = blockIdx.x * 4 + (threadIdx.x >> 6);
    const int col  = (int)lbl[row];          // wave-uniform

    const float4* xr = (const float4*)(X + (size_t)row * N_COLS);
    float4 v[8];
    #pragma unroll
    for (int k = 0; k < 8; k++) v[k] = xr[lane + 64 * k];  // 8 outstanding dwordx4

    const float lc = X[(size_t)row * N_COLS + col];  // wave-uniform target logit

    float sum = 0.f, sq = 0.f, se = 0.f;
    #pragma unroll
    for (int k = 0; k < 8; k++) {
        float e0 = v[k].x, e1 = v[k].y, e2 = v[k].z, e3 = v[k].w;
        sum += (e0 + e1) + (e2 + e3);
        sq = fmaf(e0, e0, sq); sq = fmaf(e1, e1, sq);
        sq = fmaf(e2, e2, sq); sq = fmaf(e3, e3, sq);
        se += (__expf(e0) + __expf(e1)) + (__expf(e2) + __expf(e3));
    }
    sum = wred_sum(sum);
    sq  = wred_sum(sq);
    se  = wred_sum(se);   // over ALL cols; target excluded later via se - e^lc

    if (lane == 0) row_stats[row] = make_float4(sum, sq, se, lc);
}

// Segment-sum the per-row stats into per-class accumulators. 512 KB of
// traffic + 98K atomics onto L2-resident 24 KB — a few microseconds.
__global__ __launch_bounds__(256) void k_seg(
    const long long* __restrict__ lbl, const float4* __restrict__ row_stats,
    float* __restrict__ g_sum, float* __restrict__ g_sq, float* __restrict__ g_cnt)
{
    int n = blockIdx.x * 256 + threadIdx.x;
    if (n >= N_ROWS) return;
    int c = (int)lbl[n];
    float4 rs = row_stats[n];
    atomicAdd(&g_sum[c], rs.x);
    atomicAdd(&g_sq[c],  rs.y);
    atomicAdd(&g_cnt[c], 1.0f);
}

// Per-row epilogue: m[c] inline from class sums, exclude target exp,
// margin-adjust, lse, mean into out[0].
__global__ __launch_bounds__(256) void k_nll(
    const long long* __restrict__ lbl,
    const float* __restrict__ g_sum, const float* __restrict__ g_sq,
    const float* __restrict__ g_cnt, const float4* __restrict__ row_stats,
    float* __restrict__ out)
{
    float acc = 0.f;
    for (int n = blockIdx.x * blockDim.x + threadIdx.x; n < N_ROWS;
         n += gridDim.x * blockDim.x) {
        int   c    = (int)lbl[n];
        float4 rs  = row_stats[n];
        float cnt  = fmaxf(g_cnt[c] * (float)N_COLS, 1.0f);
        float mean = g_sum[c] / cnt;
        float var  = fmaxf(g_sq[c] / cnt - mean * mean, 0.0f);
        float mm   = 0.5f * sqrtf(var);
        float x    = rs.w;
        float xm   = x - mm;
        float val  = (x > 0.f) ? (xm / S_CONST) : (xm * S_CONST);
        float se_x = fmaxf(rs.z - expf(x), 1e-30f);  // exclude target col
        float lse  = logf(se_x + expf(val));
        acc += (lse - val);
    }
    __shared__ float sh[4];
    float w = wred_sum(acc);
    int wave = threadIdx.x >> 6, lane = threadIdx.x & 63;
    if (lane == 0) sh[wave] = w;
    __syncthreads();
    if (threadIdx.x == 0) {
        float b = sh[0] + sh[1] + sh[2] + sh[3];
        atomicAdd(out, b * (1.0f / (float)N_ROWS));
    }
}

extern "C" void kernel_launch(void* const* d_in, const int* in_sizes, int n_in,
                              void* d_out, int out_size, void* d_ws, size_t ws_size,
                              hipStream_t stream) {
    const float*     X   = (const float*)d_in[0];
    const long long* lbl = (const long long*)d_in[1];
    float*           out = (float*)d_out;
    float*           ws  = (float*)d_ws;

    const int C = N_COLS, N = N_ROWS;
    float*  g_sum     = ws;
    float*  g_sq      = ws + C;
    float*  g_cnt     = ws + 2 * C;
    float4* row_stats = (float4*)(ws + 3 * C);  // 24 KB offset, 16B-aligned

    k_init<<<(3 * C + 255) / 256, 256, 0, stream>>>(ws, out);
    k_rowpass<<<N / 4, 256, 0, stream>>>(X, lbl, row_stats);
    k_seg<<<N / 256, 256, 0, stream>>>(lbl, row_stats, g_sum, g_sq, g_cnt);
    k_nll<<<64, 256, 0, stream>>>(lbl, g_sum, g_sq, g_cnt, row_stats, out);
}